// Round 7
// baseline (562.750 us; speedup 1.0000x reference)
//
#include <hip/hip_runtime.h>
#include <math.h>

#define Bn 4
#define Sn 8192
#define Dn 768
#define NSUB 4096
#define EG 32768

// ---- workspace layout (bytes) ----
#define OFF_COUNTS   0
#define OFF_OFFSETS  131072
#define OFF_POS      262144
#define OFF_DINV     393216
#define OFF_CSRT     524288
#define OFF_CSRW     1572864
#define OFF_WT       2621440
#define OFF_AGR      7340032
#define AGR_SLOT     (NSUB*Dn*4)
#define WS_A_END     (OFF_AGR + 8*AGR_SLOT)

typedef __attribute__((ext_vector_type(8))) short short8;
typedef __attribute__((ext_vector_type(4))) short short4v;
typedef __attribute__((ext_vector_type(4))) float f32x4;

__device__ __forceinline__ unsigned short bf16_rne(float v){
    unsigned u = __float_as_uint(v);
    return (unsigned short)((u + 0x7FFFu + ((u >> 16) & 1u)) >> 16);
}
__device__ __forceinline__ void split2(float v, unsigned short& h, unsigned short& l){
    h = bf16_rne(v);
    float hf = __uint_as_float(((unsigned)h) << 16);
    l = bf16_rne(v - hf);
}
__device__ __forceinline__ void fma4(float4& a, float w, const float4& v){
    a.x = fmaf(w, v.x, a.x); a.y = fmaf(w, v.y, a.y);
    a.z = fmaf(w, v.z, a.z); a.w = fmaf(w, v.w, a.w);
}

__global__ __launch_bounds__(256) void k_zero(int* __restrict__ p, int v, int n){
    int i = blockIdx.x*256 + threadIdx.x;
    if (i < n) p[i] = v;
}

__global__ __launch_bounds__(256) void k_copy(const float4* __restrict__ in,
                                              float4* __restrict__ out, int n4){
    int stride = gridDim.x*256;
    for (int i = blockIdx.x*256 + threadIdx.x; i < n4; i += stride) out[i] = in[i];
}

__global__ __launch_bounds__(256) void k_count(const int* __restrict__ eie,
                                               const int* __restrict__ ein,
                                               int* __restrict__ counts){
    int gi = blockIdx.z; int g = gi >> 2, b = gi & 3;
    const int* dst = (g ? ein : eie) + ((size_t)b*2 + 1)*EG;
    int* c = counts + gi*NSUB;
    for (int e = blockIdx.x*256 + threadIdx.x; e < EG; e += gridDim.x*256)
        atomicAdd(&c[dst[e]], 1);
}

__global__ __launch_bounds__(256) void k_scan(const int* __restrict__ counts,
                                              int* __restrict__ offsets,
                                              int* __restrict__ pos,
                                              float* __restrict__ dinv){
    int gi = blockIdx.x;
    int t  = threadIdx.x;
    __shared__ int part[256];
    const int* c = counts + gi*NSUB;
    int loc[16]; int s = 0;
    int base = t*16;
    #pragma unroll
    for (int j=0;j<16;j++){ loc[j] = s; s += c[base+j]; }
    part[t] = s;
    __syncthreads();
    for (int off=1; off<256; off<<=1){
        int v = 0;
        if (t >= off) v = part[t-off];
        __syncthreads();
        if (t >= off) part[t] += v;
        __syncthreads();
    }
    int prefix = (t==0) ? 0 : part[t-1];
    #pragma unroll
    for (int j=0;j<16;j++){
        int o = prefix + loc[j];
        offsets[gi*NSUB + base + j] = o;
        pos[gi*NSUB + base + j]     = o;
        dinv[gi*NSUB + base + j]    = 1.0f / sqrtf((float)(c[base+j] + 1));
    }
}

// counting-sort edges; store composed token index + src weight
__global__ __launch_bounds__(256) void k_fill(const int* __restrict__ eie,
                                              const int* __restrict__ ein,
                                              const int* __restrict__ t2e,
                                              const int* __restrict__ t2n,
                                              int* __restrict__ pos,
                                              const float* __restrict__ dinv,
                                              int* __restrict__ cst,
                                              float* __restrict__ csw){
    int gi = blockIdx.z; int g = gi >> 2, b = gi & 3;
    const int* ei = (g ? ein : eie) + (size_t)b*2*EG;
    const int* map_in = (g ? t2n : t2e) + b*NSUB;
    const float* dv = dinv + gi*NSUB;
    int* p  = pos + gi*NSUB;
    int*   ct = cst + (size_t)gi*EG;
    float* cw = csw + (size_t)gi*EG;
    for (int e = blockIdx.x*256 + threadIdx.x; e < EG; e += gridDim.x*256){
        int src = ei[e], d = ei[EG + e];
        int q = atomicAdd(&p[d], 1);
        ct[q] = map_in[src];
        cw[q] = dv[src];
    }
}

__global__ __launch_bounds__(256) void k_wsplit(const float* __restrict__ We,
                                                const float* __restrict__ Wn,
                                                unsigned short* __restrict__ WT){
    __shared__ float tile[32][33];
    int g = blockIdx.z;
    const float* W = g ? Wn : We;
    int k0 = blockIdx.x*32, n0 = blockIdx.y*32;
    int tx = threadIdx.x & 31, ty = threadIdx.x >> 5;
    for (int r = ty; r < 32; r += 8) tile[r][tx] = W[(size_t)(k0 + r)*Dn + n0 + tx];
    __syncthreads();
    unsigned short* hi = WT + (size_t)g*2*Dn*Dn;
    unsigned short* lo = hi + (size_t)Dn*Dn;
    for (int r = ty; r < 32; r += 8){
        float v = tile[tx][r];
        unsigned short h, l;
        split2(v, h, l);
        hi[(size_t)(n0 + r)*Dn + k0 + tx] = h;
        lo[(size_t)(n0 + r)*Dn + k0 + tx] = l;
    }
}

// sparse-first aggregation: agr[z][i] = di*( di*T[tok_i] + sum_e w_e * T[tok_e] )
// one wave per dst row, full D row, 4-deep pipelined edge loop.
__global__ __launch_bounds__(256) void k_aggT(const float* __restrict__ T,
                                              const int* __restrict__ t2e,
                                              const int* __restrict__ t2n,
                                              const int* __restrict__ cst,
                                              const float* __restrict__ csw,
                                              const int* __restrict__ offsets,
                                              const float* __restrict__ dinv,
                                              float* __restrict__ agr, int gi0){
    int z = blockIdx.z; int gi = gi0 + z;
    int g = gi >> 2, b = gi & 3;
    int wid = threadIdx.x >> 6, lane = threadIdx.x & 63;
    int i = blockIdx.x*4 + wid;
    const int* map_in = (g ? t2n : t2e) + b*NSUB;
    const float* X = T + (size_t)b*Sn*Dn;
    const int*   ct = cst + (size_t)gi*EG;
    const float* cw = csw + (size_t)gi*EG;

    int start = offsets[gi*NSUB + i];
    int end   = (i == NSUB-1) ? EG : offsets[gi*NSUB + i + 1];
    float di  = dinv[gi*NSUB + i];

    int tok = map_in[i];
    const float4* xr = (const float4*)(X + (size_t)tok*Dn);
    float4 a0 = xr[lane], a1 = xr[64+lane], a2 = xr[128+lane];
    float4 acc0 = make_float4(di*a0.x, di*a0.y, di*a0.z, di*a0.w);
    float4 acc1 = make_float4(di*a1.x, di*a1.y, di*a1.z, di*a1.w);
    float4 acc2 = make_float4(di*a2.x, di*a2.y, di*a2.z, di*a2.w);

    int e = start;
    for (; e + 4 <= end; e += 4){
        int t0_ = ct[e], t1_ = ct[e+1], t2_ = ct[e+2], t3_ = ct[e+3];
        float w0 = cw[e], w1 = cw[e+1], w2 = cw[e+2], w3 = cw[e+3];
        const float4* p0 = (const float4*)(X + (size_t)t0_*Dn);
        const float4* p1 = (const float4*)(X + (size_t)t1_*Dn);
        const float4* p2 = (const float4*)(X + (size_t)t2_*Dn);
        const float4* p3 = (const float4*)(X + (size_t)t3_*Dn);
        float4 r00 = p0[lane], r01 = p0[64+lane], r02 = p0[128+lane];
        float4 r10 = p1[lane], r11 = p1[64+lane], r12 = p1[128+lane];
        float4 r20 = p2[lane], r21 = p2[64+lane], r22 = p2[128+lane];
        float4 r30 = p3[lane], r31 = p3[64+lane], r32 = p3[128+lane];
        fma4(acc0, w0, r00); fma4(acc1, w0, r01); fma4(acc2, w0, r02);
        fma4(acc0, w1, r10); fma4(acc1, w1, r11); fma4(acc2, w1, r12);
        fma4(acc0, w2, r20); fma4(acc1, w2, r21); fma4(acc2, w2, r22);
        fma4(acc0, w3, r30); fma4(acc1, w3, r31); fma4(acc2, w3, r32);
    }
    for (; e < end; e++){
        int tk = ct[e];
        float w = cw[e];
        const float4* xs = (const float4*)(X + (size_t)tk*Dn);
        fma4(acc0, w, xs[lane]);
        fma4(acc1, w, xs[64+lane]);
        fma4(acc2, w, xs[128+lane]);
    }

    float4* o = (float4*)(agr + ((size_t)z*NSUB + i)*Dn);
    o[lane]      = make_float4(di*acc0.x, di*acc0.y, di*acc0.z, di*acc0.w);
    o[64+lane]   = make_float4(di*acc1.x, di*acc1.y, di*acc1.z, di*acc1.w);
    o[128+lane]  = make_float4(di*acc2.x, di*acc2.y, di*acc2.z, di*acc2.w);
}

// split-bf16 3-pass MFMA GEMM on dense agr rows; epilogue scatter-RMW into out:
// out[b][omap[row]] += gate * (acc + bias)
__global__ __launch_bounds__(256) void k_gemm(const float* __restrict__ A,
                                              const int* __restrict__ e2t,
                                              const int* __restrict__ n2t,
                                              const unsigned short* __restrict__ WT,
                                              const float* __restrict__ be,
                                              const float* __restrict__ bnn,
                                              const float* __restrict__ ga,
                                              const float* __restrict__ gb,
                                              float* __restrict__ out, int gi0){
    int z = blockIdx.z; int gi = gi0 + z;
    int g = gi >> 2, b = gi & 3;
    const float* Ag = A + (size_t)z*NSUB*Dn;
    const int* omap = (g ? n2t : e2t) + b*NSUB;
    const float* bias = g ? bnn : be;
    float gate = tanhf(g ? gb[0] : ga[0]);
    const unsigned short* WTh = WT + (size_t)g*2*Dn*Dn;
    const unsigned short* WTl = WTh + (size_t)Dn*Dn;

    __shared__ unsigned short AsH[128*32], AsL[128*32], BsH[128*32], BsL[128*32];
    __shared__ int rowsOut[128];

    int bm = blockIdx.x*128, bn = blockIdx.y*128;
    int tid = threadIdx.x;
    if (tid < 128) rowsOut[tid] = omap[bm + tid];

    int lane = tid & 63, wid = tid >> 6;
    int wm = (wid >> 1)*64, wn = (wid & 1)*64;

    const float* aptr[4]; int aidx[4];
    #pragma unroll
    for (int l=0;l<4;l++){
        int lin = tid + l*256;
        int row = lin >> 3, f = lin & 7;
        aptr[l] = Ag + (size_t)(bm + row)*Dn + f*4;
        int c = f >> 1, cp = c ^ ((row >> 1) & 3);
        aidx[l] = row*32 + cp*8 + (f&1)*4;
    }
    int bsrc[2], bdst[2];
    #pragma unroll
    for (int l=0;l<2;l++){
        int ci = tid + l*256;
        int n = ci >> 2, c = ci & 3;
        int cp = c ^ ((n >> 1) & 3);
        bsrc[l] = (bn + n)*Dn + c*8;
        bdst[l] = n*32 + cp*8;
    }
    int aoff[4], boff[4];
    int kc = lane >> 4;
    #pragma unroll
    for (int mt=0; mt<4; mt++){
        int r = wm + mt*16 + (lane & 15);
        aoff[mt] = r*32 + (kc ^ ((r >> 1) & 3))*8;
    }
    #pragma unroll
    for (int nt=0; nt<4; nt++){
        int cn = wn + nt*16 + (lane & 15);
        boff[nt] = cn*32 + (kc ^ ((cn >> 1) & 3))*8;
    }

    f32x4 acc[4][4];
    #pragma unroll
    for (int i=0;i<4;i++)
        #pragma unroll
        for (int j=0;j<4;j++)
            acc[i][j] = f32x4{0.f,0.f,0.f,0.f};

    for (int k0 = 0; k0 < Dn; k0 += 32){
        #pragma unroll
        for (int l=0;l<4;l++){
            float4 v = *(const float4*)(aptr[l] + k0);
            short4v h, lo;
            unsigned short hh, ll;
            split2(v.x, hh, ll); h.x = (short)hh; lo.x = (short)ll;
            split2(v.y, hh, ll); h.y = (short)hh; lo.y = (short)ll;
            split2(v.z, hh, ll); h.z = (short)hh; lo.z = (short)ll;
            split2(v.w, hh, ll); h.w = (short)hh; lo.w = (short)ll;
            *(short4v*)&AsH[aidx[l]] = h;
            *(short4v*)&AsL[aidx[l]] = lo;
        }
        #pragma unroll
        for (int l=0;l<2;l++){
            *(short8*)&BsH[bdst[l]] = *(const short8*)&WTh[bsrc[l] + k0];
            *(short8*)&BsL[bdst[l]] = *(const short8*)&WTl[bsrc[l] + k0];
        }
        __syncthreads();

        short8 ah[4], al[4];
        #pragma unroll
        for (int mt=0; mt<4; mt++){
            ah[mt] = *(const short8*)&AsH[aoff[mt]];
            al[mt] = *(const short8*)&AsL[aoff[mt]];
        }
        #pragma unroll
        for (int nt=0; nt<4; nt++){
            short8 bh = *(const short8*)&BsH[boff[nt]];
            short8 bl = *(const short8*)&BsL[boff[nt]];
            #pragma unroll
            for (int mt=0; mt<4; mt++){
                acc[mt][nt] = __builtin_amdgcn_mfma_f32_16x16x32_bf16(ah[mt], bh, acc[mt][nt], 0, 0, 0);
                acc[mt][nt] = __builtin_amdgcn_mfma_f32_16x16x32_bf16(al[mt], bh, acc[mt][nt], 0, 0, 0);
                acc[mt][nt] = __builtin_amdgcn_mfma_f32_16x16x32_bf16(ah[mt], bl, acc[mt][nt], 0, 0, 0);
            }
        }
        __syncthreads();
    }

    int r0 = (lane >> 4)*4, cc = lane & 15;
    float bv[4];
    #pragma unroll
    for (int nt=0; nt<4; nt++) bv[nt] = bias[bn + wn + cc + nt*16];
    #pragma unroll
    for (int mt=0; mt<4; mt++){
        #pragma unroll
        for (int j=0; j<4; j++){
            int rl = wm + mt*16 + r0 + j;
            int tokr = rowsOut[rl];
            float* orow = out + ((size_t)b*Sn + tokr)*Dn + bn + wn + cc;
            #pragma unroll
            for (int nt=0; nt<4; nt++)
                orow[nt*16] += gate*(acc[mt][nt][j] + bv[nt]);
        }
    }
}

extern "C" void kernel_launch(void* const* d_in, const int* in_sizes, int n_in,
                              void* d_out, int out_size, void* d_ws, size_t ws_size,
                              hipStream_t stream){
    const float* T   = (const float*)d_in[0];
    const int*   t2e = (const int*)d_in[1];
    const int*   e2t = (const int*)d_in[2];
    const int*   t2n = (const int*)d_in[3];
    const int*   n2t = (const int*)d_in[4];
    const int*   eie = (const int*)d_in[5];
    const int*   ein = (const int*)d_in[6];
    const float* We  = (const float*)d_in[7];
    const float* be  = (const float*)d_in[8];
    const float* Wn  = (const float*)d_in[9];
    const float* bnn = (const float*)d_in[10];
    const float* ga  = (const float*)d_in[11];
    const float* gb  = (const float*)d_in[12];
    float* out = (float*)d_out;

    char* ws = (char*)d_ws;
    int*   counts  = (int*)(ws + OFF_COUNTS);
    int*   offsets = (int*)(ws + OFF_OFFSETS);
    int*   pos     = (int*)(ws + OFF_POS);
    float* dinv    = (float*)(ws + OFF_DINV);
    int*   cst     = (int*)(ws + OFF_CSRT);
    float* csw     = (float*)(ws + OFF_CSRW);
    unsigned short* WT = (unsigned short*)(ws + OFF_WT);
    float* agr     = (float*)(ws + OFF_AGR);

    bool tierA = ws_size >= (size_t)WS_A_END;

    k_zero<<<dim3((8*NSUB+255)/256), 256, 0, stream>>>(counts, 0, 8*NSUB);
    k_count<<<dim3(32,1,8), 256, 0, stream>>>(eie, ein, counts);
    k_wsplit<<<dim3(24,24,2), 256, 0, stream>>>(We, Wn, WT);
    k_scan<<<dim3(8), 256, 0, stream>>>(counts, offsets, pos, dinv);
    k_fill<<<dim3(32,1,8), 256, 0, stream>>>(eie, ein, t2e, t2n, pos, dinv, cst, csw);

    int n4 = Bn*Sn*Dn/4;
    k_copy<<<dim3(2048), 256, 0, stream>>>((const float4*)T, (float4*)out, n4);

    if (tierA){
        k_aggT<<<dim3(1024,1,8), 256, 0, stream>>>(T, t2e, t2n, cst, csw, offsets, dinv, agr, 0);
        k_gemm<<<dim3(32,6,4), 256, 0, stream>>>(agr, e2t, n2t, WT, be, bnn, ga, gb, out, 0);
        k_gemm<<<dim3(32,6,4), 256, 0, stream>>>(agr + (size_t)4*NSUB*Dn, e2t, n2t, WT, be, bnn, ga, gb, out, 4);
    } else {
        for (int gi = 0; gi < 8; ++gi){
            k_aggT<<<dim3(1024,1,1), 256, 0, stream>>>(T, t2e, t2n, cst, csw, offsets, dinv, agr, gi);
            k_gemm<<<dim3(32,6,1), 256, 0, stream>>>(agr, e2t, n2t, WT, be, bnn, ga, gb, out, gi);
        }
    }
}

// Round 8
// 493.491 us; speedup vs baseline: 1.1403x; 1.1403x over previous
//
#include <hip/hip_runtime.h>
#include <math.h>

#define Bn 4
#define Sn 8192
#define Dn 768
#define NSUB 4096
#define EG 32768

// ---- workspace layout (bytes) ----
#define OFF_COUNTS   0
#define OFF_OFFSETS  131072
#define OFF_POS      262144
#define OFF_DINV     393216
#define OFF_CSRT     524288
#define OFF_CSRW     1572864
#define OFF_WT       2621440
#define OFF_INV      7340032
#define OFF_AGR      7602176
#define SLOT_B       12582912                 // NSUB*Dn*4
#define SLOT_F       (NSUB*Dn)
#define OFF_AGR2_T1  (OFF_AGR + 8*SLOT_B)     // 108265472
#define WS1_END      (OFF_AGR2_T1 + 8*SLOT_B) // 208928768
#define OFF_AGR2_T2  (OFF_AGR + 4*SLOT_B)     // 57933824
#define WS2_END      (OFF_AGR2_T2 + 4*SLOT_B) // 108265472  (proven to fit)
#define OFF_AGR2_T3  (OFF_AGR + SLOT_B)
#define WS3_END      (OFF_AGR2_T3 + SLOT_B)

typedef __attribute__((ext_vector_type(8))) short short8;
typedef __attribute__((ext_vector_type(4))) short short4v;
typedef __attribute__((ext_vector_type(4))) float f32x4;

__device__ __forceinline__ unsigned short bf16_rne(float v){
    unsigned u = __float_as_uint(v);
    return (unsigned short)((u + 0x7FFFu + ((u >> 16) & 1u)) >> 16);
}
__device__ __forceinline__ void split2(float v, unsigned short& h, unsigned short& l){
    h = bf16_rne(v);
    float hf = __uint_as_float(((unsigned)h) << 16);
    l = bf16_rne(v - hf);
}
__device__ __forceinline__ void fma4(float4& a, float w, const float4& v){
    a.x = fmaf(w, v.x, a.x); a.y = fmaf(w, v.y, a.y);
    a.z = fmaf(w, v.z, a.z); a.w = fmaf(w, v.w, a.w);
}
__device__ __forceinline__ void add4(float4& a, const float4& v){
    a.x += v.x; a.y += v.y; a.z += v.z; a.w += v.w;
}

__global__ __launch_bounds__(256) void k_zero(int* __restrict__ p, int v, int n){
    int i = blockIdx.x*256 + threadIdx.x;
    if (i < n) p[i] = v;
}

__global__ __launch_bounds__(256) void k_copy(const float4* __restrict__ in,
                                              float4* __restrict__ out, int n4){
    int stride = gridDim.x*256;
    for (int i = blockIdx.x*256 + threadIdx.x; i < n4; i += stride) out[i] = in[i];
}

__global__ __launch_bounds__(256) void k_count(const int* __restrict__ eie,
                                               const int* __restrict__ ein,
                                               int* __restrict__ counts){
    int gi = blockIdx.z; int g = gi >> 2, b = gi & 3;
    const int* dst = (g ? ein : eie) + ((size_t)b*2 + 1)*EG;
    int* c = counts + gi*NSUB;
    for (int e = blockIdx.x*256 + threadIdx.x; e < EG; e += gridDim.x*256)
        atomicAdd(&c[dst[e]], 1);
}

__global__ __launch_bounds__(256) void k_scan(const int* __restrict__ counts,
                                              int* __restrict__ offsets,
                                              int* __restrict__ pos,
                                              float* __restrict__ dinv){
    int gi = blockIdx.x;
    int t  = threadIdx.x;
    __shared__ int part[256];
    const int* c = counts + gi*NSUB;
    int loc[16]; int s = 0;
    int base = t*16;
    #pragma unroll
    for (int j=0;j<16;j++){ loc[j] = s; s += c[base+j]; }
    part[t] = s;
    __syncthreads();
    for (int off=1; off<256; off<<=1){
        int v = 0;
        if (t >= off) v = part[t-off];
        __syncthreads();
        if (t >= off) part[t] += v;
        __syncthreads();
    }
    int prefix = (t==0) ? 0 : part[t-1];
    #pragma unroll
    for (int j=0;j<16;j++){
        int o = prefix + loc[j];
        offsets[gi*NSUB + base + j] = o;
        pos[gi*NSUB + base + j]     = o;
        dinv[gi*NSUB + base + j]    = 1.0f / sqrtf((float)(c[base+j] + 1));
    }
}

__global__ __launch_bounds__(256) void k_fill(const int* __restrict__ eie,
                                              const int* __restrict__ ein,
                                              const int* __restrict__ t2e,
                                              const int* __restrict__ t2n,
                                              int* __restrict__ pos,
                                              const float* __restrict__ dinv,
                                              int* __restrict__ cst,
                                              float* __restrict__ csw){
    int gi = blockIdx.z; int g = gi >> 2, b = gi & 3;
    const int* ei = (g ? ein : eie) + (size_t)b*2*EG;
    const int* map_in = (g ? t2n : t2e) + b*NSUB;
    const float* dv = dinv + gi*NSUB;
    int* p  = pos + gi*NSUB;
    int*   ct = cst + (size_t)gi*EG;
    float* cw = csw + (size_t)gi*EG;
    for (int e = blockIdx.x*256 + threadIdx.x; e < EG; e += gridDim.x*256){
        int src = ei[e], d = ei[EG + e];
        int q = atomicAdd(&p[d], 1);
        ct[q] = map_in[src];
        cw[q] = dv[src];
    }
}

__global__ __launch_bounds__(256) void k_inv(const int* __restrict__ e2t,
                                             const int* __restrict__ n2t,
                                             int* __restrict__ inv){
    int gi = blockIdx.z; int g = gi >> 2, b = gi & 3;
    const int* omap = (g ? n2t : e2t) + b*NSUB;
    int i = blockIdx.x*256 + threadIdx.x;
    if (i < NSUB) inv[(size_t)gi*Sn + omap[i]] = i;
}

__global__ __launch_bounds__(256) void k_wsplit(const float* __restrict__ We,
                                                const float* __restrict__ Wn,
                                                unsigned short* __restrict__ WT){
    __shared__ float tile[32][33];
    int g = blockIdx.z;
    const float* W = g ? Wn : We;
    int k0 = blockIdx.x*32, n0 = blockIdx.y*32;
    int tx = threadIdx.x & 31, ty = threadIdx.x >> 5;
    for (int r = ty; r < 32; r += 8) tile[r][tx] = W[(size_t)(k0 + r)*Dn + n0 + tx];
    __syncthreads();
    unsigned short* hi = WT + (size_t)g*2*Dn*Dn;
    unsigned short* lo = hi + (size_t)Dn*Dn;
    for (int r = ty; r < 32; r += 8){
        float v = tile[tx][r];
        unsigned short h, l;
        split2(v, h, l);
        hi[(size_t)(n0 + r)*Dn + k0 + tx] = h;
        lo[(size_t)(n0 + r)*Dn + k0 + tx] = l;
    }
}

// sparse-first aggregation: agr[z][i] = di*( di*T[tok_i] + sum_e w_e * T[tok_e] )
__global__ __launch_bounds__(256) void k_aggT(const float* __restrict__ T,
                                              const int* __restrict__ t2e,
                                              const int* __restrict__ t2n,
                                              const int* __restrict__ cst,
                                              const float* __restrict__ csw,
                                              const int* __restrict__ offsets,
                                              const float* __restrict__ dinv,
                                              float* __restrict__ agr, int gi0){
    int z = blockIdx.z; int gi = gi0 + z;
    int g = gi >> 2, b = gi & 3;
    int wid = threadIdx.x >> 6, lane = threadIdx.x & 63;
    int i = blockIdx.x*4 + wid;
    const int* map_in = (g ? t2n : t2e) + b*NSUB;
    const float* X = T + (size_t)b*Sn*Dn;
    const int*   ct = cst + (size_t)gi*EG;
    const float* cw = csw + (size_t)gi*EG;

    int start = offsets[gi*NSUB + i];
    int end   = (i == NSUB-1) ? EG : offsets[gi*NSUB + i + 1];
    float di  = dinv[gi*NSUB + i];

    int tok = map_in[i];
    const float4* xr = (const float4*)(X + (size_t)tok*Dn);
    float4 a0 = xr[lane], a1 = xr[64+lane], a2 = xr[128+lane];
    float4 acc0 = make_float4(di*a0.x, di*a0.y, di*a0.z, di*a0.w);
    float4 acc1 = make_float4(di*a1.x, di*a1.y, di*a1.z, di*a1.w);
    float4 acc2 = make_float4(di*a2.x, di*a2.y, di*a2.z, di*a2.w);

    int e = start;
    for (; e + 4 <= end; e += 4){
        int t0_ = ct[e], t1_ = ct[e+1], t2_ = ct[e+2], t3_ = ct[e+3];
        float w0 = cw[e], w1 = cw[e+1], w2 = cw[e+2], w3 = cw[e+3];
        const float4* p0 = (const float4*)(X + (size_t)t0_*Dn);
        const float4* p1 = (const float4*)(X + (size_t)t1_*Dn);
        const float4* p2 = (const float4*)(X + (size_t)t2_*Dn);
        const float4* p3 = (const float4*)(X + (size_t)t3_*Dn);
        float4 r00 = p0[lane], r01 = p0[64+lane], r02 = p0[128+lane];
        float4 r10 = p1[lane], r11 = p1[64+lane], r12 = p1[128+lane];
        float4 r20 = p2[lane], r21 = p2[64+lane], r22 = p2[128+lane];
        float4 r30 = p3[lane], r31 = p3[64+lane], r32 = p3[128+lane];
        fma4(acc0, w0, r00); fma4(acc1, w0, r01); fma4(acc2, w0, r02);
        fma4(acc0, w1, r10); fma4(acc1, w1, r11); fma4(acc2, w1, r12);
        fma4(acc0, w2, r20); fma4(acc1, w2, r21); fma4(acc2, w2, r22);
        fma4(acc0, w3, r30); fma4(acc1, w3, r31); fma4(acc2, w3, r32);
    }
    for (; e < end; e++){
        int tk = ct[e];
        float w = cw[e];
        const float4* xs = (const float4*)(X + (size_t)tk*Dn);
        fma4(acc0, w, xs[lane]);
        fma4(acc1, w, xs[64+lane]);
        fma4(acc2, w, xs[128+lane]);
    }

    float4* o = (float4*)(agr + ((size_t)z*NSUB + i)*Dn);
    o[lane]      = make_float4(di*acc0.x, di*acc0.y, di*acc0.z, di*acc0.w);
    o[64+lane]   = make_float4(di*acc1.x, di*acc1.y, di*acc1.z, di*acc1.w);
    o[128+lane]  = make_float4(di*acc2.x, di*acc2.y, di*acc2.z, di*acc2.w);
}

// split-bf16 3-pass MFMA GEMM, dense in (agr) -> dense out (agr2 = gate*(A@W + bias))
__global__ __launch_bounds__(256) void k_gemm(const float* __restrict__ A,
                                              const unsigned short* __restrict__ WT,
                                              const float* __restrict__ be,
                                              const float* __restrict__ bnn,
                                              const float* __restrict__ ga,
                                              const float* __restrict__ gb,
                                              float* __restrict__ A2, int gi0){
    int z = blockIdx.z; int gi = gi0 + z;
    int g = gi >> 2;
    const float* Ag = A + (size_t)z*SLOT_F;
    const float* bias = g ? bnn : be;
    float gate = tanhf(g ? gb[0] : ga[0]);
    const unsigned short* WTh = WT + (size_t)g*2*Dn*Dn;
    const unsigned short* WTl = WTh + (size_t)Dn*Dn;

    __shared__ unsigned short AsH[128*32], AsL[128*32], BsH[128*32], BsL[128*32];

    int bm = blockIdx.x*128, bn = blockIdx.y*128;
    int tid = threadIdx.x;
    int lane = tid & 63, wid = tid >> 6;
    int wm = (wid >> 1)*64, wn = (wid & 1)*64;

    const float* aptr[4]; int aidx[4];
    #pragma unroll
    for (int l=0;l<4;l++){
        int lin = tid + l*256;
        int row = lin >> 3, f = lin & 7;
        aptr[l] = Ag + (size_t)(bm + row)*Dn + f*4;
        int c = f >> 1, cp = c ^ ((row >> 1) & 3);
        aidx[l] = row*32 + cp*8 + (f&1)*4;
    }
    int bsrc[2], bdst[2];
    #pragma unroll
    for (int l=0;l<2;l++){
        int ci = tid + l*256;
        int n = ci >> 2, c = ci & 3;
        int cp = c ^ ((n >> 1) & 3);
        bsrc[l] = (bn + n)*Dn + c*8;
        bdst[l] = n*32 + cp*8;
    }
    int aoff[4], boff[4];
    int kc = lane >> 4;
    #pragma unroll
    for (int mt=0; mt<4; mt++){
        int r = wm + mt*16 + (lane & 15);
        aoff[mt] = r*32 + (kc ^ ((r >> 1) & 3))*8;
    }
    #pragma unroll
    for (int nt=0; nt<4; nt++){
        int cn = wn + nt*16 + (lane & 15);
        boff[nt] = cn*32 + (kc ^ ((cn >> 1) & 3))*8;
    }

    f32x4 acc[4][4];
    #pragma unroll
    for (int i=0;i<4;i++)
        #pragma unroll
        for (int j=0;j<4;j++)
            acc[i][j] = f32x4{0.f,0.f,0.f,0.f};

    for (int k0 = 0; k0 < Dn; k0 += 32){
        #pragma unroll
        for (int l=0;l<4;l++){
            float4 v = *(const float4*)(aptr[l] + k0);
            short4v h, lo;
            unsigned short hh, ll;
            split2(v.x, hh, ll); h.x = (short)hh; lo.x = (short)ll;
            split2(v.y, hh, ll); h.y = (short)hh; lo.y = (short)ll;
            split2(v.z, hh, ll); h.z = (short)hh; lo.z = (short)ll;
            split2(v.w, hh, ll); h.w = (short)hh; lo.w = (short)ll;
            *(short4v*)&AsH[aidx[l]] = h;
            *(short4v*)&AsL[aidx[l]] = lo;
        }
        #pragma unroll
        for (int l=0;l<2;l++){
            *(short8*)&BsH[bdst[l]] = *(const short8*)&WTh[bsrc[l] + k0];
            *(short8*)&BsL[bdst[l]] = *(const short8*)&WTl[bsrc[l] + k0];
        }
        __syncthreads();

        short8 ah[4], al[4];
        #pragma unroll
        for (int mt=0; mt<4; mt++){
            ah[mt] = *(const short8*)&AsH[aoff[mt]];
            al[mt] = *(const short8*)&AsL[aoff[mt]];
        }
        #pragma unroll
        for (int nt=0; nt<4; nt++){
            short8 bh = *(const short8*)&BsH[boff[nt]];
            short8 bl = *(const short8*)&BsL[boff[nt]];
            #pragma unroll
            for (int mt=0; mt<4; mt++){
                acc[mt][nt] = __builtin_amdgcn_mfma_f32_16x16x32_bf16(ah[mt], bh, acc[mt][nt], 0, 0, 0);
                acc[mt][nt] = __builtin_amdgcn_mfma_f32_16x16x32_bf16(al[mt], bh, acc[mt][nt], 0, 0, 0);
                acc[mt][nt] = __builtin_amdgcn_mfma_f32_16x16x32_bf16(ah[mt], bl, acc[mt][nt], 0, 0, 0);
            }
        }
        __syncthreads();
    }

    int r0 = (lane >> 4)*4, cc = lane & 15;
    float bv[4];
    #pragma unroll
    for (int nt=0; nt<4; nt++) bv[nt] = bias[bn + wn + cc + nt*16];
    #pragma unroll
    for (int mt=0; mt<4; mt++){
        #pragma unroll
        for (int j=0; j<4; j++){
            int row = bm + wm + mt*16 + r0 + j;
            float* orow = A2 + ((size_t)z*SLOT_F + (size_t)row*Dn) + bn + wn + cc;
            #pragma unroll
            for (int nt=0; nt<4; nt++)
                orow[nt*16] = gate*(acc[mt][nt][j] + bv[nt]);
        }
    }
}

// MODE 0: out = T + gather(ae) + gather(an); MODE 1: out = T + gather(ae);
// MODE 2: out += gather(an).   ae/an slot index = b (4 slots each).
template<int MODE>
__global__ __launch_bounds__(256) void k_scatter(const float* __restrict__ T,
                                                 const int* __restrict__ inv,
                                                 const float* __restrict__ ae,
                                                 const float* __restrict__ an,
                                                 float* __restrict__ out){
    int wid = threadIdx.x >> 6, lane = threadIdx.x & 63;
    int row = blockIdx.x*4 + wid;
    int b = row >> 13, tok = row & (Sn-1);

    float4 t0, t1, t2;
    if (MODE == 2){
        const float4* orr = (const float4*)(out + (size_t)row*Dn);
        t0 = orr[lane]; t1 = orr[64+lane]; t2 = orr[128+lane];
    } else {
        const float4* tr = (const float4*)(T + (size_t)row*Dn);
        t0 = tr[lane]; t1 = tr[64+lane]; t2 = tr[128+lane];
    }
    if (MODE != 2){
        int ie = inv[(size_t)b*Sn + tok];
        if (ie >= 0){
            const float4* er = (const float4*)(ae + (size_t)b*SLOT_F + (size_t)ie*Dn);
            add4(t0, er[lane]); add4(t1, er[64+lane]); add4(t2, er[128+lane]);
        }
    }
    if (MODE != 1){
        int in_ = inv[(size_t)(4+b)*Sn + tok];
        if (in_ >= 0){
            const float4* nr = (const float4*)(an + (size_t)b*SLOT_F + (size_t)in_*Dn);
            add4(t0, nr[lane]); add4(t1, nr[64+lane]); add4(t2, nr[128+lane]);
        }
    }
    float4* o = (float4*)(out + (size_t)row*Dn);
    o[lane] = t0; o[64+lane] = t1; o[128+lane] = t2;
}

// fallback per-graph scatter-RMW (rows unique per gi; launches serialized)
__global__ __launch_bounds__(256) void k_scat1(const float* __restrict__ a2,
                                               const int* __restrict__ e2t,
                                               const int* __restrict__ n2t,
                                               float* __restrict__ out, int gi){
    int g = gi >> 2, b = gi & 3;
    const int* omap = (g ? n2t : e2t) + b*NSUB;
    int wid = threadIdx.x >> 6, lane = threadIdx.x & 63;
    int i = blockIdx.x*4 + wid;
    int tok = omap[i];
    const float4* er = (const float4*)(a2 + (size_t)i*Dn);
    float4* o = (float4*)(out + ((size_t)b*Sn + tok)*Dn);
    float4 c0 = o[lane], c1 = o[64+lane], c2 = o[128+lane];
    add4(c0, er[lane]); add4(c1, er[64+lane]); add4(c2, er[128+lane]);
    o[lane] = c0; o[64+lane] = c1; o[128+lane] = c2;
}

extern "C" void kernel_launch(void* const* d_in, const int* in_sizes, int n_in,
                              void* d_out, int out_size, void* d_ws, size_t ws_size,
                              hipStream_t stream){
    const float* T   = (const float*)d_in[0];
    const int*   t2e = (const int*)d_in[1];
    const int*   e2t = (const int*)d_in[2];
    const int*   t2n = (const int*)d_in[3];
    const int*   n2t = (const int*)d_in[4];
    const int*   eie = (const int*)d_in[5];
    const int*   ein = (const int*)d_in[6];
    const float* We  = (const float*)d_in[7];
    const float* be  = (const float*)d_in[8];
    const float* Wn  = (const float*)d_in[9];
    const float* bnn = (const float*)d_in[10];
    const float* ga  = (const float*)d_in[11];
    const float* gb  = (const float*)d_in[12];
    float* out = (float*)d_out;

    char* ws = (char*)d_ws;
    int*   counts  = (int*)(ws + OFF_COUNTS);
    int*   offsets = (int*)(ws + OFF_OFFSETS);
    int*   pos     = (int*)(ws + OFF_POS);
    float* dinv    = (float*)(ws + OFF_DINV);
    int*   cst     = (int*)(ws + OFF_CSRT);
    float* csw     = (float*)(ws + OFF_CSRW);
    unsigned short* WT = (unsigned short*)(ws + OFF_WT);
    int*   inv     = (int*)(ws + OFF_INV);
    float* agr     = (float*)(ws + OFF_AGR);

    // common prep
    k_zero<<<dim3((8*NSUB+255)/256), 256, 0, stream>>>(counts, 0, 8*NSUB);
    k_zero<<<dim3((8*Sn+255)/256), 256, 0, stream>>>(inv, -1, 8*Sn);
    k_count<<<dim3(32,1,8), 256, 0, stream>>>(eie, ein, counts);
    k_wsplit<<<dim3(24,24,2), 256, 0, stream>>>(We, Wn, WT);
    k_inv<<<dim3(16,1,8), 256, 0, stream>>>(e2t, n2t, inv);
    k_scan<<<dim3(8), 256, 0, stream>>>(counts, offsets, pos, dinv);
    k_fill<<<dim3(32,1,8), 256, 0, stream>>>(eie, ein, t2e, t2n, pos, dinv, cst, csw);

    if (ws_size >= (size_t)WS1_END){
        float* agr2 = (float*)(ws + OFF_AGR2_T1);
        k_aggT<<<dim3(1024,1,8), 256, 0, stream>>>(T, t2e, t2n, cst, csw, offsets, dinv, agr, 0);
        k_gemm<<<dim3(32,6,8), 256, 0, stream>>>(agr, WT, be, bnn, ga, gb, agr2, 0);
        k_scatter<0><<<dim3(Bn*Sn/4), 256, 0, stream>>>(T, inv, agr2, agr2 + (size_t)4*SLOT_F, out);
    } else if (ws_size >= (size_t)WS2_END){
        float* agr2 = (float*)(ws + OFF_AGR2_T2);
        // e-half
        k_aggT<<<dim3(1024,1,4), 256, 0, stream>>>(T, t2e, t2n, cst, csw, offsets, dinv, agr, 0);
        k_gemm<<<dim3(32,6,4), 256, 0, stream>>>(agr, WT, be, bnn, ga, gb, agr2, 0);
        k_scatter<1><<<dim3(Bn*Sn/4), 256, 0, stream>>>(T, inv, agr2, agr2, out);
        // n-half (reuses agr/agr2)
        k_aggT<<<dim3(1024,1,4), 256, 0, stream>>>(T, t2e, t2n, cst, csw, offsets, dinv, agr, 4);
        k_gemm<<<dim3(32,6,4), 256, 0, stream>>>(agr, WT, be, bnn, ga, gb, agr2, 4);
        k_scatter<2><<<dim3(Bn*Sn/4), 256, 0, stream>>>(T, inv, agr2, agr2, out);
    } else {
        float* agr2 = (float*)(ws + OFF_AGR2_T3);
        int n4 = Bn*Sn*Dn/4;
        k_copy<<<dim3(2048), 256, 0, stream>>>((const float4*)T, (float4*)out, n4);
        for (int gi = 0; gi < 8; ++gi){
            k_aggT<<<dim3(1024,1,1), 256, 0, stream>>>(T, t2e, t2n, cst, csw, offsets, dinv, agr, gi);
            k_gemm<<<dim3(32,6,1), 256, 0, stream>>>(agr, WT, be, bnn, ga, gb, agr2, gi);
            k_scat1<<<dim3(1024), 256, 0, stream>>>(agr2, e2t, n2t, out, gi);
        }
    }
}

// Round 9
// 480.173 us; speedup vs baseline: 1.1720x; 1.0277x over previous
//
#include <hip/hip_runtime.h>
#include <math.h>

#define Bn 4
#define Sn 8192
#define Dn 768
#define NSUB 4096
#define EG 32768

// ---- prep workspace layout (bytes) ----
#define OFF_COUNTS   0
#define OFF_OFFSETS  131072
#define OFF_POS      262144
#define OFF_DINV     393216
#define OFF_CSRT     524288
#define OFF_CSRW     1572864
#define OFF_WT       2621440
#define OFF_INV      7340032
#define OFF_AGR      7602176
// per-slot sizes
#define SLOT_F       (NSUB*Dn)                  // floats / ushorts per slot
// tier thresholds: prep + nslot*(2B+2B+4B)*SLOT_F
#define WS_TIER(n)   ((size_t)OFF_AGR + (size_t)(n)*SLOT_F*8)

typedef __attribute__((ext_vector_type(8))) short short8;
typedef __attribute__((ext_vector_type(4))) short short4v;
typedef __attribute__((ext_vector_type(4))) float f32x4;

__device__ __forceinline__ unsigned short bf16_rne(float v){
    unsigned u = __float_as_uint(v);
    return (unsigned short)((u + 0x7FFFu + ((u >> 16) & 1u)) >> 16);
}
__device__ __forceinline__ void split2(float v, unsigned short& h, unsigned short& l){
    h = bf16_rne(v);
    float hf = __uint_as_float(((unsigned)h) << 16);
    l = bf16_rne(v - hf);
}
__device__ __forceinline__ void fma4(float4& a, float w, const float4& v){
    a.x = fmaf(w, v.x, a.x); a.y = fmaf(w, v.y, a.y);
    a.z = fmaf(w, v.z, a.z); a.w = fmaf(w, v.w, a.w);
}
__device__ __forceinline__ void add4(float4& a, const float4& v){
    a.x += v.x; a.y += v.y; a.z += v.z; a.w += v.w;
}
__device__ __forceinline__ void gload16(const void* g, void* l){
    __builtin_amdgcn_global_load_lds((const __attribute__((address_space(1))) void*)g,
                                     (__attribute__((address_space(3))) void*)l, 16, 0, 0);
}

__global__ __launch_bounds__(256) void k_zero(int* __restrict__ p, int v, int n){
    int i = blockIdx.x*256 + threadIdx.x;
    if (i < n) p[i] = v;
}

__global__ __launch_bounds__(256) void k_copy(const float4* __restrict__ in,
                                              float4* __restrict__ out, int n4){
    int stride = gridDim.x*256;
    for (int i = blockIdx.x*256 + threadIdx.x; i < n4; i += stride) out[i] = in[i];
}

__global__ __launch_bounds__(256) void k_count(const int* __restrict__ eie,
                                               const int* __restrict__ ein,
                                               int* __restrict__ counts){
    int gi = blockIdx.z; int g = gi >> 2, b = gi & 3;
    const int* dst = (g ? ein : eie) + ((size_t)b*2 + 1)*EG;
    int* c = counts + gi*NSUB;
    for (int e = blockIdx.x*256 + threadIdx.x; e < EG; e += gridDim.x*256)
        atomicAdd(&c[dst[e]], 1);
}

__global__ __launch_bounds__(256) void k_scan(const int* __restrict__ counts,
                                              int* __restrict__ offsets,
                                              int* __restrict__ pos,
                                              float* __restrict__ dinv){
    int gi = blockIdx.x;
    int t  = threadIdx.x;
    __shared__ int part[256];
    const int* c = counts + gi*NSUB;
    int loc[16]; int s = 0;
    int base = t*16;
    #pragma unroll
    for (int j=0;j<16;j++){ loc[j] = s; s += c[base+j]; }
    part[t] = s;
    __syncthreads();
    for (int off=1; off<256; off<<=1){
        int v = 0;
        if (t >= off) v = part[t-off];
        __syncthreads();
        if (t >= off) part[t] += v;
        __syncthreads();
    }
    int prefix = (t==0) ? 0 : part[t-1];
    #pragma unroll
    for (int j=0;j<16;j++){
        int o = prefix + loc[j];
        offsets[gi*NSUB + base + j] = o;
        pos[gi*NSUB + base + j]     = o;
        dinv[gi*NSUB + base + j]    = 1.0f / sqrtf((float)(c[base+j] + 1));
    }
}

__global__ __launch_bounds__(256) void k_fill(const int* __restrict__ eie,
                                              const int* __restrict__ ein,
                                              const int* __restrict__ t2e,
                                              const int* __restrict__ t2n,
                                              int* __restrict__ pos,
                                              const float* __restrict__ dinv,
                                              int* __restrict__ cst,
                                              float* __restrict__ csw){
    int gi = blockIdx.z; int g = gi >> 2, b = gi & 3;
    const int* ei = (g ? ein : eie) + (size_t)b*2*EG;
    const int* map_in = (g ? t2n : t2e) + b*NSUB;
    const float* dv = dinv + gi*NSUB;
    int* p  = pos + gi*NSUB;
    int*   ct = cst + (size_t)gi*EG;
    float* cw = csw + (size_t)gi*EG;
    for (int e = blockIdx.x*256 + threadIdx.x; e < EG; e += gridDim.x*256){
        int src = ei[e], d = ei[EG + e];
        int q = atomicAdd(&p[d], 1);
        ct[q] = map_in[src];
        cw[q] = dv[src];
    }
}

__global__ __launch_bounds__(256) void k_inv(const int* __restrict__ e2t,
                                             const int* __restrict__ n2t,
                                             int* __restrict__ inv){
    int gi = blockIdx.z; int g = gi >> 2, b = gi & 3;
    const int* omap = (g ? n2t : e2t) + b*NSUB;
    int i = blockIdx.x*256 + threadIdx.x;
    if (i < NSUB) inv[(size_t)gi*Sn + omap[i]] = i;
}

__global__ __launch_bounds__(256) void k_wsplit(const float* __restrict__ We,
                                                const float* __restrict__ Wn,
                                                unsigned short* __restrict__ WT){
    __shared__ float tile[32][33];
    int g = blockIdx.z;
    const float* W = g ? Wn : We;
    int k0 = blockIdx.x*32, n0 = blockIdx.y*32;
    int tx = threadIdx.x & 31, ty = threadIdx.x >> 5;
    for (int r = ty; r < 32; r += 8) tile[r][tx] = W[(size_t)(k0 + r)*Dn + n0 + tx];
    __syncthreads();
    unsigned short* hi = WT + (size_t)g*2*Dn*Dn;
    unsigned short* lo = hi + (size_t)Dn*Dn;
    for (int r = ty; r < 32; r += 8){
        float v = tile[tx][r];
        unsigned short h, l;
        split2(v, h, l);
        hi[(size_t)(n0 + r)*Dn + k0 + tx] = h;
        lo[(size_t)(n0 + r)*Dn + k0 + tx] = l;
    }
}

// sparse-first aggregation; epilogue pre-splits to bf16 hi/lo for the GEMM.
__global__ __launch_bounds__(256) void k_aggT(const float* __restrict__ T,
                                              const int* __restrict__ t2e,
                                              const int* __restrict__ t2n,
                                              const int* __restrict__ cst,
                                              const float* __restrict__ csw,
                                              const int* __restrict__ offsets,
                                              const float* __restrict__ dinv,
                                              unsigned short* __restrict__ agrH,
                                              unsigned short* __restrict__ agrL,
                                              int gi0){
    int z = blockIdx.z; int gi = gi0 + z;
    int g = gi >> 2, b = gi & 3;
    int wid = threadIdx.x >> 6, lane = threadIdx.x & 63;
    int i = blockIdx.x*4 + wid;
    const int* map_in = (g ? t2n : t2e) + b*NSUB;
    const float* X = T + (size_t)b*Sn*Dn;
    const int*   ct = cst + (size_t)gi*EG;
    const float* cw = csw + (size_t)gi*EG;

    int start = offsets[gi*NSUB + i];
    int end   = (i == NSUB-1) ? EG : offsets[gi*NSUB + i + 1];
    float di  = dinv[gi*NSUB + i];

    int tok = map_in[i];
    const float4* xr = (const float4*)(X + (size_t)tok*Dn);
    float4 a0 = xr[lane], a1 = xr[64+lane], a2 = xr[128+lane];
    float4 acc0 = make_float4(di*a0.x, di*a0.y, di*a0.z, di*a0.w);
    float4 acc1 = make_float4(di*a1.x, di*a1.y, di*a1.z, di*a1.w);
    float4 acc2 = make_float4(di*a2.x, di*a2.y, di*a2.z, di*a2.w);

    int e = start;
    for (; e + 4 <= end; e += 4){
        int t0_ = ct[e], t1_ = ct[e+1], t2_ = ct[e+2], t3_ = ct[e+3];
        float w0 = cw[e], w1 = cw[e+1], w2 = cw[e+2], w3 = cw[e+3];
        const float4* p0 = (const float4*)(X + (size_t)t0_*Dn);
        const float4* p1 = (const float4*)(X + (size_t)t1_*Dn);
        const float4* p2 = (const float4*)(X + (size_t)t2_*Dn);
        const float4* p3 = (const float4*)(X + (size_t)t3_*Dn);
        float4 r00 = p0[lane], r01 = p0[64+lane], r02 = p0[128+lane];
        float4 r10 = p1[lane], r11 = p1[64+lane], r12 = p1[128+lane];
        float4 r20 = p2[lane], r21 = p2[64+lane], r22 = p2[128+lane];
        float4 r30 = p3[lane], r31 = p3[64+lane], r32 = p3[128+lane];
        fma4(acc0, w0, r00); fma4(acc1, w0, r01); fma4(acc2, w0, r02);
        fma4(acc0, w1, r10); fma4(acc1, w1, r11); fma4(acc2, w1, r12);
        fma4(acc0, w2, r20); fma4(acc1, w2, r21); fma4(acc2, w2, r22);
        fma4(acc0, w3, r30); fma4(acc1, w3, r31); fma4(acc2, w3, r32);
    }
    for (; e < end; e++){
        int tk = ct[e];
        float w = cw[e];
        const float4* xs = (const float4*)(X + (size_t)tk*Dn);
        fma4(acc0, w, xs[lane]);
        fma4(acc1, w, xs[64+lane]);
        fma4(acc2, w, xs[128+lane]);
    }

    size_t rb = ((size_t)z*NSUB + i)*Dn;
    unsigned short h, l;
    short4v H, L;
    split2(di*acc0.x, h, l); H.x=(short)h; L.x=(short)l;
    split2(di*acc0.y, h, l); H.y=(short)h; L.y=(short)l;
    split2(di*acc0.z, h, l); H.z=(short)h; L.z=(short)l;
    split2(di*acc0.w, h, l); H.w=(short)h; L.w=(short)l;
    *(short4v*)&agrH[rb + lane*4] = H; *(short4v*)&agrL[rb + lane*4] = L;
    split2(di*acc1.x, h, l); H.x=(short)h; L.x=(short)l;
    split2(di*acc1.y, h, l); H.y=(short)h; L.y=(short)l;
    split2(di*acc1.z, h, l); H.z=(short)h; L.z=(short)l;
    split2(di*acc1.w, h, l); H.w=(short)h; L.w=(short)l;
    *(short4v*)&agrH[rb + 256 + lane*4] = H; *(short4v*)&agrL[rb + 256 + lane*4] = L;
    split2(di*acc2.x, h, l); H.x=(short)h; L.x=(short)l;
    split2(di*acc2.y, h, l); H.y=(short)h; L.y=(short)l;
    split2(di*acc2.z, h, l); H.z=(short)h; L.z=(short)l;
    split2(di*acc2.w, h, l); H.w=(short)h; L.w=(short)l;
    *(short4v*)&agrH[rb + 512 + lane*4] = H; *(short4v*)&agrL[rb + 512 + lane*4] = L;
}

// split-bf16 3-pass MFMA GEMM, pre-split bf16 inputs, global_load_lds staging.
// 128x128 tile, BK=32; wave w stages buffer w (8 chunks of 1KB each).
__global__ __launch_bounds__(256) void k_gemm(const unsigned short* __restrict__ agrH,
                                              const unsigned short* __restrict__ agrL,
                                              const unsigned short* __restrict__ WT,
                                              const float* __restrict__ be,
                                              const float* __restrict__ bnn,
                                              const float* __restrict__ ga,
                                              const float* __restrict__ gb,
                                              float* __restrict__ A2, int gi0){
    int z = blockIdx.z; int gi = gi0 + z;
    int g = gi >> 2;
    const unsigned short* AH = agrH + (size_t)z*SLOT_F;
    const unsigned short* AL = agrL + (size_t)z*SLOT_F;
    const float* bias = g ? bnn : be;
    float gate = tanhf(g ? gb[0] : ga[0]);
    const unsigned short* WTh = WT + (size_t)g*2*Dn*Dn;
    const unsigned short* WTl = WTh + (size_t)Dn*Dn;

    __shared__ unsigned short AsH[128*32], AsL[128*32], BsH[128*32], BsL[128*32];

    int bm = blockIdx.x*128, bn = blockIdx.y*128;
    int tid = threadIdx.x;
    int lane = tid & 63, wid = tid >> 6;
    int wm = (wid >> 1)*64, wn = (wid & 1)*64;

    // staging assignment: wave 0->AsH, 1->AsL, 2->BsH, 3->BsL
    const unsigned short* gbase;
    unsigned short* lbase;
    if      (wid == 0){ gbase = AH  + (size_t)bm*Dn; lbase = AsH; }
    else if (wid == 1){ gbase = AL  + (size_t)bm*Dn; lbase = AsL; }
    else if (wid == 2){ gbase = WTh + (size_t)bn*Dn; lbase = BsH; }
    else              { gbase = WTl + (size_t)bn*Dn; lbase = BsL; }
    int srow  = lane >> 2;          // 0..15
    int skoff = (lane & 3)*8;       // ushort offset 0..24

    int aoff[4], boff[4];
    int kc = lane >> 4;
    #pragma unroll
    for (int mt=0; mt<4; mt++){
        int r = wm + mt*16 + (lane & 15);
        aoff[mt] = r*32 + kc*8;
    }
    #pragma unroll
    for (int nt=0; nt<4; nt++){
        int cn = wn + nt*16 + (lane & 15);
        boff[nt] = cn*32 + kc*8;
    }

    f32x4 acc[4][4];
    #pragma unroll
    for (int i=0;i<4;i++)
        #pragma unroll
        for (int j=0;j<4;j++)
            acc[i][j] = f32x4{0.f,0.f,0.f,0.f};

    for (int k0 = 0; k0 < Dn; k0 += 32){
        #pragma unroll
        for (int c=0;c<8;c++){
            const unsigned short* src = gbase + (size_t)(c*16 + srow)*Dn + k0 + skoff;
            gload16(src, lbase + c*512);
        }
        __syncthreads();

        short8 ah[4], al[4];
        #pragma unroll
        for (int mt=0; mt<4; mt++){
            ah[mt] = *(const short8*)&AsH[aoff[mt]];
            al[mt] = *(const short8*)&AsL[aoff[mt]];
        }
        #pragma unroll
        for (int nt=0; nt<4; nt++){
            short8 bh = *(const short8*)&BsH[boff[nt]];
            short8 bl = *(const short8*)&BsL[boff[nt]];
            #pragma unroll
            for (int mt=0; mt<4; mt++){
                acc[mt][nt] = __builtin_amdgcn_mfma_f32_16x16x32_bf16(ah[mt], bh, acc[mt][nt], 0, 0, 0);
                acc[mt][nt] = __builtin_amdgcn_mfma_f32_16x16x32_bf16(al[mt], bh, acc[mt][nt], 0, 0, 0);
                acc[mt][nt] = __builtin_amdgcn_mfma_f32_16x16x32_bf16(ah[mt], bl, acc[mt][nt], 0, 0, 0);
            }
        }
        __syncthreads();
    }

    int r0 = (lane >> 4)*4, cc = lane & 15;
    float bv[4];
    #pragma unroll
    for (int nt=0; nt<4; nt++) bv[nt] = bias[bn + wn + cc + nt*16];
    #pragma unroll
    for (int mt=0; mt<4; mt++){
        #pragma unroll
        for (int j=0; j<4; j++){
            int row = bm + wm + mt*16 + r0 + j;
            float* orow = A2 + ((size_t)z*SLOT_F + (size_t)row*Dn) + bn + wn + cc;
            #pragma unroll
            for (int nt=0; nt<4; nt++)
                orow[nt*16] = gate*(acc[mt][nt][j] + bv[nt]);
        }
    }
}

// MODE 0: out = T + gather(ae) + gather(an); MODE 1: out = T + gather(ae);
// MODE 2: out += gather(an).
template<int MODE>
__global__ __launch_bounds__(256) void k_scatter(const float* __restrict__ T,
                                                 const int* __restrict__ inv,
                                                 const float* __restrict__ ae,
                                                 const float* __restrict__ an,
                                                 float* __restrict__ out){
    int wid = threadIdx.x >> 6, lane = threadIdx.x & 63;
    int row = blockIdx.x*4 + wid;
    int b = row >> 13, tok = row & (Sn-1);

    float4 t0, t1, t2;
    if (MODE == 2){
        const float4* orr = (const float4*)(out + (size_t)row*Dn);
        t0 = orr[lane]; t1 = orr[64+lane]; t2 = orr[128+lane];
    } else {
        const float4* tr = (const float4*)(T + (size_t)row*Dn);
        t0 = tr[lane]; t1 = tr[64+lane]; t2 = tr[128+lane];
    }
    if (MODE != 2){
        int ie = inv[(size_t)b*Sn + tok];
        if (ie >= 0){
            const float4* er = (const float4*)(ae + (size_t)b*SLOT_F + (size_t)ie*Dn);
            add4(t0, er[lane]); add4(t1, er[64+lane]); add4(t2, er[128+lane]);
        }
    }
    if (MODE != 1){
        int in_ = inv[(size_t)(4+b)*Sn + tok];
        if (in_ >= 0){
            const float4* nr = (const float4*)(an + (size_t)b*SLOT_F + (size_t)in_*Dn);
            add4(t0, nr[lane]); add4(t1, nr[64+lane]); add4(t2, nr[128+lane]);
        }
    }
    float4* o = (float4*)(out + (size_t)row*Dn);
    o[lane] = t0; o[64+lane] = t1; o[128+lane] = t2;
}

// fallback per-graph scatter-RMW
__global__ __launch_bounds__(256) void k_scat1(const float* __restrict__ a2,
                                               const int* __restrict__ e2t,
                                               const int* __restrict__ n2t,
                                               float* __restrict__ out, int gi){
    int g = gi >> 2, b = gi & 3;
    const int* omap = (g ? n2t : e2t) + b*NSUB;
    int wid = threadIdx.x >> 6, lane = threadIdx.x & 63;
    int i = blockIdx.x*4 + wid;
    int tok = omap[i];
    const float4* er = (const float4*)(a2 + (size_t)i*Dn);
    float4* o = (float4*)(out + ((size_t)b*Sn + tok)*Dn);
    float4 c0 = o[lane], c1 = o[64+lane], c2 = o[128+lane];
    add4(c0, er[lane]); add4(c1, er[64+lane]); add4(c2, er[128+lane]);
    o[lane] = c0; o[64+lane] = c1; o[128+lane] = c2;
}

extern "C" void kernel_launch(void* const* d_in, const int* in_sizes, int n_in,
                              void* d_out, int out_size, void* d_ws, size_t ws_size,
                              hipStream_t stream){
    const float* T   = (const float*)d_in[0];
    const int*   t2e = (const int*)d_in[1];
    const int*   e2t = (const int*)d_in[2];
    const int*   t2n = (const int*)d_in[3];
    const int*   n2t = (const int*)d_in[4];
    const int*   eie = (const int*)d_in[5];
    const int*   ein = (const int*)d_in[6];
    const float* We  = (const float*)d_in[7];
    const float* be  = (const float*)d_in[8];
    const float* Wn  = (const float*)d_in[9];
    const float* bnn = (const float*)d_in[10];
    const float* ga  = (const float*)d_in[11];
    const float* gb  = (const float*)d_in[12];
    float* out = (float*)d_out;

    char* ws = (char*)d_ws;
    int*   counts  = (int*)(ws + OFF_COUNTS);
    int*   offsets = (int*)(ws + OFF_OFFSETS);
    int*   pos     = (int*)(ws + OFF_POS);
    float* dinv    = (float*)(ws + OFF_DINV);
    int*   cst     = (int*)(ws + OFF_CSRT);
    float* csw     = (float*)(ws + OFF_CSRW);
    unsigned short* WT = (unsigned short*)(ws + OFF_WT);
    int*   inv     = (int*)(ws + OFF_INV);

    // common prep
    k_zero<<<dim3((8*NSUB+255)/256), 256, 0, stream>>>(counts, 0, 8*NSUB);
    k_zero<<<dim3((8*Sn+255)/256), 256, 0, stream>>>(inv, -1, 8*Sn);
    k_count<<<dim3(32,1,8), 256, 0, stream>>>(eie, ein, counts);
    k_wsplit<<<dim3(24,24,2), 256, 0, stream>>>(We, Wn, WT);
    k_inv<<<dim3(16,1,8), 256, 0, stream>>>(e2t, n2t, inv);
    k_scan<<<dim3(8), 256, 0, stream>>>(counts, offsets, pos, dinv);
    k_fill<<<dim3(32,1,8), 256, 0, stream>>>(eie, ein, t2e, t2n, pos, dinv, cst, csw);

    size_t usl = (size_t)SLOT_F;
    if (ws_size >= WS_TIER(8)){
        unsigned short* agrH = (unsigned short*)(ws + OFF_AGR);
        unsigned short* agrL = agrH + 8*usl;
        float* agr2 = (float*)(agrL + 8*usl);
        k_aggT<<<dim3(1024,1,8), 256, 0, stream>>>(T, t2e, t2n, cst, csw, offsets, dinv, agrH, agrL, 0);
        k_gemm<<<dim3(32,6,8), 256, 0, stream>>>(agrH, agrL, WT, be, bnn, ga, gb, agr2, 0);
        k_scatter<0><<<dim3(Bn*Sn/4), 256, 0, stream>>>(T, inv, agr2, agr2 + 4*usl, out);
    } else if (ws_size >= WS_TIER(4)){
        unsigned short* agrH = (unsigned short*)(ws + OFF_AGR);
        unsigned short* agrL = agrH + 4*usl;
        float* agr2 = (float*)(agrL + 4*usl);
        k_aggT<<<dim3(1024,1,4), 256, 0, stream>>>(T, t2e, t2n, cst, csw, offsets, dinv, agrH, agrL, 0);
        k_gemm<<<dim3(32,6,4), 256, 0, stream>>>(agrH, agrL, WT, be, bnn, ga, gb, agr2, 0);
        k_scatter<1><<<dim3(Bn*Sn/4), 256, 0, stream>>>(T, inv, agr2, agr2, out);
        k_aggT<<<dim3(1024,1,4), 256, 0, stream>>>(T, t2e, t2n, cst, csw, offsets, dinv, agrH, agrL, 4);
        k_gemm<<<dim3(32,6,4), 256, 0, stream>>>(agrH, agrL, WT, be, bnn, ga, gb, agr2, 4);
        k_scatter<2><<<dim3(Bn*Sn/4), 256, 0, stream>>>(T, inv, agr2, agr2, out);
    } else {
        unsigned short* agrH = (unsigned short*)(ws + OFF_AGR);
        unsigned short* agrL = agrH + usl;
        float* agr2 = (float*)(agrL + usl);
        int n4 = Bn*Sn*Dn/4;
        k_copy<<<dim3(2048), 256, 0, stream>>>((const float4*)T, (float4*)out, n4);
        for (int gi = 0; gi < 8; ++gi){
            k_aggT<<<dim3(1024,1,1), 256, 0, stream>>>(T, t2e, t2n, cst, csw, offsets, dinv, agrH, agrL, gi);
            k_gemm<<<dim3(32,6,1), 256, 0, stream>>>(agrH, agrL, WT, be, bnn, ga, gb, agr2, gi);
            k_scat1<<<dim3(1024), 256, 0, stream>>>(agr2, e2t, n2t, out, gi);
        }
    }
}